// Round 12
// baseline (3882.523 us; speedup 1.0000x reference)
//
#include <hip/hip_runtime.h>

#define BATCH 64
#define TSEQ  4096
#define MROWS (BATCH * TSEQ)   // 262144
#define HD    256
#define G3    768

typedef unsigned short u16;
typedef unsigned int   u32;
typedef __attribute__((ext_vector_type(8))) short bf16x8;
typedef __attribute__((ext_vector_type(4))) float f32x4;

__device__ __forceinline__ float bf2f(u16 x) {
  union { u32 u; float f; } v; v.u = ((u32)x) << 16; return v.f;
}
__device__ __forceinline__ u16 f2bf(float x) {
  union { float f; u32 u; } v; v.f = x;
  u32 r = (v.u + 0x7fffu + ((v.u >> 16) & 1u)) >> 16;
  return (u16)r;
}
__device__ __forceinline__ float fsig(float x) {
  float e = __expf(-x);
  return __builtin_amdgcn_rcpf(1.0f + e);
}
__device__ __forceinline__ float ftanh(float x) {
  float e = __expf(-2.0f * x);
  return 2.0f * __builtin_amdgcn_rcpf(1.0f + e) - 1.0f;
}

#define M_NSEG 0
#define M_CNT 8
#define M_CUR 80

// ---- prep2: LDS-tiled coalesced transpose f32 -> bf16 [N][K]; block 0 zeros meta ----
__global__ __launch_bounds__(256) void k_prep2(const float* __restrict__ Wx,
    const float* __restrict__ Wh, const float* __restrict__ Wo,
    u16* __restrict__ WxT, u16* __restrict__ WhT, u16* __restrict__ WoT,
    int* __restrict__ meta) {
  __shared__ float t[64][65];
  int bid = blockIdx.x;
  if (bid == 0) meta[threadIdx.x] = 0;
  const float* src; u16* dst; int W; int tile;
  if (bid < 48)      { src = Wx; dst = WxT; W = G3; tile = bid; }
  else if (bid < 96) { src = Wh; dst = WhT; W = G3; tile = bid - 48; }
  else               { src = Wo; dst = WoT; W = HD; tile = bid - 96; }
  int ntn = W / 64;
  int kb = (tile / ntn) * 64, nb = (tile % ntn) * 64;
  int r = threadIdx.x >> 6, c = threadIdx.x & 63;
  #pragma unroll
  for (int p = 0; p < 16; p++)
    t[p * 4 + r][c] = src[(size_t)(kb + p * 4 + r) * W + nb + c];
  __syncthreads();
  #pragma unroll
  for (int p = 0; p < 16; p++)
    dst[(size_t)(nb + p * 4 + r) * HD + kb + c] = f2bf(t[c][p * 4 + r]);
}

// ---- conv: b_batch f32 -> bf16 ----
__global__ __launch_bounds__(256) void k_conv(const float* __restrict__ src,
                                              u16* __restrict__ dst) {
  size_t i = (size_t)blockIdx.x * 256 + threadIdx.x;
  size_t stride = (size_t)gridDim.x * 256;
  const size_t n8 = (size_t)MROWS * HD / 8;
  for (; i < n8; i += stride) {
    float4 a = ((const float4*)src)[2 * i];
    float4 b = ((const float4*)src)[2 * i + 1];
    ushort4 lo, hi;
    lo.x = f2bf(a.x); lo.y = f2bf(a.y); lo.z = f2bf(a.z); lo.w = f2bf(a.w);
    hi.x = f2bf(b.x); hi.y = f2bf(b.y); hi.z = f2bf(b.z); hi.w = f2bf(b.w);
    ((ushort4*)dst)[2 * i] = lo;
    ((ushort4*)dst)[2 * i + 1] = hi;
  }
}

// ---- segment discovery + histogram (validated) ----
__global__ __launch_bounds__(256) void k_find(const float* __restrict__ is_summ,
    u32* __restrict__ tmp, int* __restrict__ meta) {
  int idx = blockIdx.x * 256 + threadIdx.x;
  if (idx >= MROWS) return;
  int b = idx >> 12, t = idx & 4095;
  bool start = (t == 0) || (is_summ[idx - 1] != 0.0f);
  if (!start) return;
  int tt = t;
  while (tt < 4095 && is_summ[(b << 12) + tt] == 0.0f) tt++;
  int L = tt - t + 1;
  int slot = atomicAdd(&meta[M_NSEG], 1);
  tmp[slot] = (u32)idx | ((u32)L << 18);
  int bk = L < 64 ? L : 64;
  atomicAdd(&meta[M_CNT + bk], 1);
}

__global__ void k_buckets(int* __restrict__ meta) {
  if (threadIdx.x != 0) return;
  int acc = 0;
  for (int L = 64; L >= 1; --L) {
    meta[M_CUR + L] = acc;
    acc += meta[M_CNT + L];
  }
}

__global__ __launch_bounds__(256) void k_scatter(const u32* __restrict__ tmp,
    u32* __restrict__ sorted, int* __restrict__ meta) {
  int n = meta[M_NSEG];
  int stride = gridDim.x * 256;
  for (int i = blockIdx.x * 256 + threadIdx.x; i < n; i += stride) {
    u32 rec = tmp[i];
    int L = (int)(rec >> 18);
    int bk = L < 64 ? L : 64;
    int slot = atomicAdd(&meta[M_CUR + bk], 1);
    sorted[slot] = rec;
  }
}

// ---- MFMA GEMM (validated R10/R11): 128x64 tile, XCD swizzle ----
template<int N, bool ABF, bool STOREF32>
__global__ __launch_bounds__(256) void k_gemm(const void* __restrict__ Ap,
    const u16* __restrict__ BT, const float* __restrict__ bias,
    void* __restrict__ Cp) {
  constexpr int NB = N / 64;
  constexpr int NWG = (MROWS / 128) * NB;
  constexpr int CPX = NWG / 8;
  int bid = blockIdx.x;
  int wg = (bid & 7) * CPX + (bid >> 3);
  int mb = wg / NB, nb = wg % NB;
  int wv = threadIdx.x >> 6, lane = threadIdx.x & 63;
  int lr = lane & 15, lk = (lane >> 4) * 8;
  int m0 = mb * 128 + wv * 32;
  int n0 = nb * 64;
  const float* A32 = (const float*)Ap;
  const u16*   A16 = (const u16*)Ap;
  f32x4 acc[2][4] = {};
  #pragma unroll
  for (int kk = 0; kk < 8; kk++) {
    bf16x8 a0, a1;
    if constexpr (ABF) {
      a0 = *(const bf16x8*)(A16 + (size_t)(m0 + lr) * HD + kk * 32 + lk);
      a1 = *(const bf16x8*)(A16 + (size_t)(m0 + 16 + lr) * HD + kk * 32 + lk);
    } else {
      const float* r0p = A32 + (size_t)(m0 + lr) * HD + kk * 32 + lk;
      const float* r1p = A32 + (size_t)(m0 + 16 + lr) * HD + kk * 32 + lk;
      float4 x0 = *(const float4*)r0p, x1 = *(const float4*)(r0p + 4);
      float4 y0 = *(const float4*)r1p, y1 = *(const float4*)(r1p + 4);
      a0[0]=(short)f2bf(x0.x); a0[1]=(short)f2bf(x0.y); a0[2]=(short)f2bf(x0.z); a0[3]=(short)f2bf(x0.w);
      a0[4]=(short)f2bf(x1.x); a0[5]=(short)f2bf(x1.y); a0[6]=(short)f2bf(x1.z); a0[7]=(short)f2bf(x1.w);
      a1[0]=(short)f2bf(y0.x); a1[1]=(short)f2bf(y0.y); a1[2]=(short)f2bf(y0.z); a1[3]=(short)f2bf(y0.w);
      a1[4]=(short)f2bf(y1.x); a1[5]=(short)f2bf(y1.y); a1[6]=(short)f2bf(y1.z); a1[7]=(short)f2bf(y1.w);
    }
    #pragma unroll
    for (int ns = 0; ns < 4; ns++) {
      bf16x8 bv = *(const bf16x8*)(BT + (size_t)(n0 + ns * 16 + lr) * HD + kk * 32 + lk);
      acc[0][ns] = __builtin_amdgcn_mfma_f32_16x16x32_bf16(a0, bv, acc[0][ns], 0, 0, 0);
      acc[1][ns] = __builtin_amdgcn_mfma_f32_16x16x32_bf16(a1, bv, acc[1][ns], 0, 0, 0);
    }
  }
  #pragma unroll
  for (int mi = 0; mi < 2; mi++) {
    int r0 = m0 + mi * 16 + (lane >> 4) * 4;
    #pragma unroll
    for (int ns = 0; ns < 4; ns++) {
      int col = n0 + ns * 16 + lr;
      float bv = bias[col];
      #pragma unroll
      for (int i = 0; i < 4; i++) {
        float v = acc[mi][ns][i] + bv;
        if constexpr (STOREF32) ((float*)Cp)[(size_t)(r0 + i) * N + col] = v;
        else ((u16*)Cp)[(size_t)(r0 + i) * N + col] = f2bf(v);
      }
    }
  }
}

// ---- scan4: 4 waves/block, f32 carry in regs, bf16 h in LDS, fused out-GEMM ----
__global__ __launch_bounds__(256, 2) void k_scan4(const u16* __restrict__ gx,
    const u16* __restrict__ WhT, const u16* __restrict__ WoT,
    const float* __restrict__ bh, const float* __restrict__ bo,
    const float* __restrict__ is_summ, float* __restrict__ out,
    float* __restrict__ h_last, const u32* __restrict__ sorted,
    const int* __restrict__ meta) {
  __shared__ u16 hbf[4][16][256];   // 32 KB, chunk-8 XOR swizzled cols
  __shared__ u16 sbuf[12288];       // 24 KB (Wh window)
  __shared__ int lmsh[4];
  int nseg = meta[M_NSEG];
  int tid = threadIdx.x;
  int wv = tid >> 6, lane = tid & 63;
  int lr = lane & 15, g2 = lane >> 4, lk = g2 * 8;
  int sbase = (blockIdx.x * 4 + wv) * 16;

  int gsv[4], Lv[4];
  #pragma unroll
  for (int i = 0; i < 4; i++) {
    int s = sbase + g2 * 4 + i;
    u32 rec = (s < nseg) ? sorted[s] : 0u;
    gsv[i] = (int)(rec & 0x3FFFFu);
    Lv[i]  = (s < nseg) ? (int)(rec >> 18) : 0;
  }
  int lm = max(max(Lv[0], Lv[1]), max(Lv[2], Lv[3]));
  #pragma unroll
  for (int off = 32; off; off >>= 1) lm = max(lm, __shfl_xor(lm, off));
  if (lane == 0) lmsh[wv] = lm;
  __syncthreads();
  int lmb = max(max(lmsh[0], lmsh[1]), max(lmsh[2], lmsh[3]));
  if (lmb == 0) return;

  float hreg[4][16];   // [i][w] f32 carry — all indices compile-time (rule #20)
  bf16x8 af[8];

  for (int k = 0; k < lmb; k++) {
    bool act = (k < lm);
    if (k == 0) {
      #pragma unroll
      for (int w = 0; w < 16; w++) {
        int col = w * 16 + lr;
        float bhr = bh[col], bhz = bh[col + 256], bhn = bh[col + 512];
        #pragma unroll
        for (int i = 0; i < 4; i++) {
          float hnew = 0.0f;
          if (Lv[i] > 0) {
            int gidx = gsv[i];
            float gr = bf2f(gx[(size_t)gidx * G3 + col]);
            float gz = bf2f(gx[(size_t)gidx * G3 + 256 + col]);
            float gn = bf2f(gx[(size_t)gidx * G3 + 512 + col]);
            float r = fsig(gr + bhr);
            float z = fsig(gz + bhz);
            float nn = ftanh(gn + r * bhn);
            hnew = (1.0f - z) * nn;
            if (((gidx + 1) & 4095) == 0) {
              float m = 1.0f - is_summ[gidx];
              h_last[(size_t)(gidx >> 12) * HD + col] = m * hnew;
            }
          }
          hreg[i][w] = hnew;
          int row = g2 * 4 + i;
          hbf[wv][row][col ^ ((row & 7) << 3)] = f2bf(hnew);
        }
      }
    } else {
      #pragma unroll
      for (int w = 0; w < 16; w++) {
        #pragma unroll
        for (int p = 0; p < 6; p++) {     // 1536 chunks / 256 threads
          int L = p * 256 + tid;
          int gate = L >> 9, rem = L & 511;
          int r = rem >> 5, c = rem & 31;
          *(uint4*)&sbuf[gate * 4096 + r * 256 + ((c ^ (r & 7)) * 8)] =
              *(const uint4*)&WhT[((size_t)(gate << 8) + w * 16 + r) * 256 + c * 8];
        }
        __syncthreads();
        if (act) {
          f32x4 ar = {0,0,0,0}, az = {0,0,0,0}, an = {0,0,0,0};
          #pragma unroll
          for (int kk = 0; kk < 8; kk++) {
            int ch = ((kk * 4 + g2) ^ (lr & 7)) * 8;
            bf16x8 b0 = *(const bf16x8*)&sbuf[lr * 256 + ch];
            bf16x8 b1 = *(const bf16x8*)&sbuf[4096 + lr * 256 + ch];
            bf16x8 b2 = *(const bf16x8*)&sbuf[8192 + lr * 256 + ch];
            ar = __builtin_amdgcn_mfma_f32_16x16x32_bf16(af[kk], b0, ar, 0, 0, 0);
            az = __builtin_amdgcn_mfma_f32_16x16x32_bf16(af[kk], b1, az, 0, 0, 0);
            an = __builtin_amdgcn_mfma_f32_16x16x32_bf16(af[kk], b2, an, 0, 0, 0);
          }
          int col = w * 16 + lr;
          float bhr = bh[col], bhz = bh[col + 256], bhn = bh[col + 512];
          #pragma unroll
          for (int i = 0; i < 4; i++) {
            if (k < Lv[i]) {
              int gidx = gsv[i] + k;
              float gr = bf2f(gx[(size_t)gidx * G3 + col]);
              float gz = bf2f(gx[(size_t)gidx * G3 + 256 + col]);
              float gn = bf2f(gx[(size_t)gidx * G3 + 512 + col]);
              float hp = hreg[i][w];
              float r = fsig(gr + ar[i] + bhr);
              float z = fsig(gz + az[i] + bhz);
              float nn = ftanh(gn + r * (an[i] + bhn));
              float hnew = (1.0f - z) * nn + z * hp;
              hreg[i][w] = hnew;
              if (((gidx + 1) & 4095) == 0) {
                float m = 1.0f - is_summ[gidx];
                h_last[(size_t)(gidx >> 12) * HD + col] = m * hnew;
              }
            }
          }
        }
        __syncthreads();
      }
      #pragma unroll
      for (int w = 0; w < 16; w++)
        #pragma unroll
        for (int i = 0; i < 4; i++) {
          int row = g2 * 4 + i;
          hbf[wv][row][(w * 16 + lr) ^ ((row & 7) << 3)] = f2bf(hreg[i][w]);
        }
    }
    __syncthreads();   // hbf visible for af build (barrier count uniform per k)
    #pragma unroll
    for (int kk = 0; kk < 8; kk++)
      af[kk] = *(const bf16x8*)&hbf[wv][lr][(kk * 32 + lk) ^ ((lr & 7) << 3)];
    // ---- out phase: B-frags direct from L2-resident WoT; no LDS, no barriers ----
    #pragma unroll
    for (int w = 0; w < 16; w++) {
      if (act) {
        f32x4 ao = {0,0,0,0};
        const u16* wr = WoT + (size_t)(w * 16 + lr) * HD + lk;
        #pragma unroll
        for (int kk = 0; kk < 8; kk++) {
          bf16x8 bv = *(const bf16x8*)(wr + kk * 32);
          ao = __builtin_amdgcn_mfma_f32_16x16x32_bf16(af[kk], bv, ao, 0, 0, 0);
        }
        int col = w * 16 + lr;
        float bov = bo[col];
        #pragma unroll
        for (int i = 0; i < 4; i++)
          if (k < Lv[i])
            out[(size_t)(gsv[i] + k) * HD + col] = ao[i] + bov;
      }
    }
  }
}

extern "C" void kernel_launch(void* const* d_in, const int* in_sizes, int n_in,
                              void* d_out, int out_size, void* d_ws, size_t ws_size,
                              hipStream_t stream) {
  const int exp_sizes[8] = {BATCH * TSEQ * HD, BATCH * TSEQ, HD * G3, HD * G3,
                            G3, G3, HD * HD, HD};
  if (n_in != 8) return;
  for (int i = 0; i < 8; i++)
    if (in_sizes[i] != exp_sizes[i]) return;

  const float* b_batch = (const float*)d_in[0];
  const float* is_summ = (const float*)d_in[1];
  const float* Wx = (const float*)d_in[2];
  const float* Wh = (const float*)d_in[3];
  const float* bx = (const float*)d_in[4];
  const float* bh = (const float*)d_in[5];
  const float* Wo = (const float*)d_in[6];
  const float* bo = (const float*)d_in[7];

  float* out = (float*)d_out;
  float* h_last = out + (size_t)MROWS * HD;

  char* ws = (char*)d_ws;
  size_t o = 0;
  u16* gx     = (u16*)(ws + o); o += (size_t)MROWS * G3 * 2;   // 402,653,184
  u16* Abf    = (u16*)(ws + o); o += (size_t)MROWS * HD * 2;   // 134,217,728
  u16* WxT    = (u16*)(ws + o); o += (size_t)G3 * HD * 2;
  u16* WhT    = (u16*)(ws + o); o += (size_t)G3 * HD * 2;
  u16* WoT    = (u16*)(ws + o); o += (size_t)HD * HD * 2;
  int* meta   = (int*)(ws + o); o += 1024;
  u32* tmp    = (u32*)(ws + o); o += (size_t)MROWS * 4;
  u32* sorted = (u32*)(ws + o); o += (size_t)MROWS * 4;
  if (ws_size < o) return;

  k_prep2<<<112, 256, 0, stream>>>(Wx, Wh, Wo, WxT, WhT, WoT, meta);
  k_conv<<<2048, 256, 0, stream>>>(b_batch, Abf);
  k_find<<<MROWS / 256, 256, 0, stream>>>(is_summ, tmp, meta);
  k_buckets<<<1, 64, 0, stream>>>(meta);
  k_scatter<<<256, 256, 0, stream>>>(tmp, sorted, meta);
  k_gemm<G3, true, false><<<(MROWS / 128) * (G3 / 64), 256, 0, stream>>>(Abf, WxT, bx, gx);
  k_scan4<<<MROWS / 64, 256, 0, stream>>>(gx, WhT, WoT, bh, bo, is_summ,
                                          out, h_last, sorted, meta);
}

// Round 13
// 3605.463 us; speedup vs baseline: 1.0768x; 1.0768x over previous
//
#include <hip/hip_runtime.h>

#define BATCH 64
#define TSEQ  4096
#define MROWS (BATCH * TSEQ)   // 262144
#define HD    256
#define G3    768

typedef unsigned short u16;
typedef unsigned int   u32;
typedef __attribute__((ext_vector_type(8))) short bf16x8;
typedef __attribute__((ext_vector_type(4))) float f32x4;

__device__ __forceinline__ float bf2f(u16 x) {
  union { u32 u; float f; } v; v.u = ((u32)x) << 16; return v.f;
}
__device__ __forceinline__ u16 f2bf(float x) {
  union { float f; u32 u; } v; v.f = x;
  u32 r = (v.u + 0x7fffu + ((v.u >> 16) & 1u)) >> 16;
  return (u16)r;
}
__device__ __forceinline__ float fsig(float x) {
  float e = __expf(-x);
  return __builtin_amdgcn_rcpf(1.0f + e);
}
__device__ __forceinline__ float ftanh(float x) {
  float e = __expf(-2.0f * x);
  return 2.0f * __builtin_amdgcn_rcpf(1.0f + e) - 1.0f;
}
__device__ __forceinline__ bf16x8 pack8(float4 a, float4 b) {
  bf16x8 r;
  r[0] = (short)f2bf(a.x); r[1] = (short)f2bf(a.y);
  r[2] = (short)f2bf(a.z); r[3] = (short)f2bf(a.w);
  r[4] = (short)f2bf(b.x); r[5] = (short)f2bf(b.y);
  r[6] = (short)f2bf(b.z); r[7] = (short)f2bf(b.w);
  return r;
}

#define M_NSEG 0
#define M_CNT 8
#define M_CUR 80

// h LDS col swizzle (validated R10): address computed PER float4.
#define HCOL(r, c) ((c) ^ (((r) & 7) << 2))

// ---- prep2: LDS-tiled coalesced transpose f32 -> bf16 [N][K]; block 0 zeros meta ----
__global__ __launch_bounds__(256) void k_prep2(const float* __restrict__ Wx,
    const float* __restrict__ Wh, const float* __restrict__ Wo,
    u16* __restrict__ WxT, u16* __restrict__ WhT, u16* __restrict__ WoT,
    int* __restrict__ meta) {
  __shared__ float t[64][65];
  int bid = blockIdx.x;
  if (bid == 0) meta[threadIdx.x] = 0;
  const float* src; u16* dst; int W; int tile;
  if (bid < 48)      { src = Wx; dst = WxT; W = G3; tile = bid; }
  else if (bid < 96) { src = Wh; dst = WhT; W = G3; tile = bid - 48; }
  else               { src = Wo; dst = WoT; W = HD; tile = bid - 96; }
  int ntn = W / 64;
  int kb = (tile / ntn) * 64, nb = (tile % ntn) * 64;
  int r = threadIdx.x >> 6, c = threadIdx.x & 63;
  #pragma unroll
  for (int p = 0; p < 16; p++)
    t[p * 4 + r][c] = src[(size_t)(kb + p * 4 + r) * W + nb + c];
  __syncthreads();
  #pragma unroll
  for (int p = 0; p < 16; p++)
    dst[(size_t)(nb + p * 4 + r) * HD + kb + c] = f2bf(t[c][p * 4 + r]);
}

// ---- conv: b_batch f32 -> bf16 ----
__global__ __launch_bounds__(256) void k_conv(const float* __restrict__ src,
                                              u16* __restrict__ dst) {
  size_t i = (size_t)blockIdx.x * 256 + threadIdx.x;
  size_t stride = (size_t)gridDim.x * 256;
  const size_t n8 = (size_t)MROWS * HD / 8;
  for (; i < n8; i += stride) {
    float4 a = ((const float4*)src)[2 * i];
    float4 b = ((const float4*)src)[2 * i + 1];
    ushort4 lo, hi;
    lo.x = f2bf(a.x); lo.y = f2bf(a.y); lo.z = f2bf(a.z); lo.w = f2bf(a.w);
    hi.x = f2bf(b.x); hi.y = f2bf(b.y); hi.z = f2bf(b.z); hi.w = f2bf(b.w);
    ((ushort4*)dst)[2 * i] = lo;
    ((ushort4*)dst)[2 * i + 1] = hi;
  }
}

// ---- segment discovery + histogram (validated) ----
__global__ __launch_bounds__(256) void k_find(const float* __restrict__ is_summ,
    u32* __restrict__ tmp, int* __restrict__ meta) {
  int idx = blockIdx.x * 256 + threadIdx.x;
  if (idx >= MROWS) return;
  int b = idx >> 12, t = idx & 4095;
  bool start = (t == 0) || (is_summ[idx - 1] != 0.0f);
  if (!start) return;
  int tt = t;
  while (tt < 4095 && is_summ[(b << 12) + tt] == 0.0f) tt++;
  int L = tt - t + 1;
  int slot = atomicAdd(&meta[M_NSEG], 1);
  tmp[slot] = (u32)idx | ((u32)L << 18);
  int bk = L < 64 ? L : 64;
  atomicAdd(&meta[M_CNT + bk], 1);
}

__global__ void k_buckets(int* __restrict__ meta) {
  if (threadIdx.x != 0) return;
  int acc = 0;
  for (int L = 64; L >= 1; --L) {
    meta[M_CUR + L] = acc;
    acc += meta[M_CNT + L];
  }
}

__global__ __launch_bounds__(256) void k_scatter(const u32* __restrict__ tmp,
    u32* __restrict__ sorted, int* __restrict__ meta) {
  int n = meta[M_NSEG];
  int stride = gridDim.x * 256;
  for (int i = blockIdx.x * 256 + threadIdx.x; i < n; i += stride) {
    u32 rec = tmp[i];
    int L = (int)(rec >> 18);
    int bk = L < 64 ? L : 64;
    int slot = atomicAdd(&meta[M_CUR + bk], 1);
    sorted[slot] = rec;
  }
}

// ---- MFMA GEMM (validated R10-R12): 128x64 tile, XCD swizzle, bf16 A ----
template<int N>
__global__ __launch_bounds__(256) void k_gemm(const u16* __restrict__ A,
    const u16* __restrict__ BT, const float* __restrict__ bias,
    u16* __restrict__ C) {
  constexpr int NB = N / 64;
  constexpr int NWG = (MROWS / 128) * NB;
  constexpr int CPX = NWG / 8;
  int bid = blockIdx.x;
  int wg = (bid & 7) * CPX + (bid >> 3);
  int mb = wg / NB, nb = wg % NB;
  int wv = threadIdx.x >> 6, lane = threadIdx.x & 63;
  int lr = lane & 15, lk = (lane >> 4) * 8;
  int m0 = mb * 128 + wv * 32;
  int n0 = nb * 64;
  f32x4 acc[2][4] = {};
  #pragma unroll
  for (int kk = 0; kk < 8; kk++) {
    bf16x8 a0 = *(const bf16x8*)(A + (size_t)(m0 + lr) * HD + kk * 32 + lk);
    bf16x8 a1 = *(const bf16x8*)(A + (size_t)(m0 + 16 + lr) * HD + kk * 32 + lk);
    #pragma unroll
    for (int ns = 0; ns < 4; ns++) {
      bf16x8 bv = *(const bf16x8*)(BT + (size_t)(n0 + ns * 16 + lr) * HD + kk * 32 + lk);
      acc[0][ns] = __builtin_amdgcn_mfma_f32_16x16x32_bf16(a0, bv, acc[0][ns], 0, 0, 0);
      acc[1][ns] = __builtin_amdgcn_mfma_f32_16x16x32_bf16(a1, bv, acc[1][ns], 0, 0, 0);
    }
  }
  #pragma unroll
  for (int mi = 0; mi < 2; mi++) {
    int r0 = m0 + mi * 16 + (lane >> 4) * 4;
    #pragma unroll
    for (int ns = 0; ns < 4; ns++) {
      int col = n0 + ns * 16 + lr;
      float bv = bias[col];
      #pragma unroll
      for (int i = 0; i < 4; i++)
        C[(size_t)(r0 + i) * N + col] = f2bf(acc[mi][ns][i] + bv);
    }
  }
}

// ---- scan5: 1 wave/block, 16 segments, ZERO barriers. h f32 in wave-private ----
// LDS (16 KB -> ~10 blocks/CU). Wh/Wo B-fragments read DIRECTLY from L2-resident
// transposed weights. Numerics identical to scan3 (f32 carry, bf16 af via pack8).
__global__ __launch_bounds__(64) void k_scan5(const u16* __restrict__ gx,
    const u16* __restrict__ WhT, const u16* __restrict__ WoT,
    const float* __restrict__ bh, const float* __restrict__ bo,
    const float* __restrict__ is_summ, float* __restrict__ out,
    float* __restrict__ h_last, const u32* __restrict__ sorted,
    const int* __restrict__ meta) {
  __shared__ float h[16][256];    // 16 KB, wave-private (1 wave per block)
  int nseg = meta[M_NSEG];
  int lane = threadIdx.x;
  int lr = lane & 15, g2 = lane >> 4, lk = g2 * 8;
  int sbase = blockIdx.x * 16;
  if (sbase >= nseg) return;

  int gsv[4], Lv[4];
  #pragma unroll
  for (int i = 0; i < 4; i++) {
    int s = sbase + g2 * 4 + i;
    u32 rec = (s < nseg) ? sorted[s] : 0u;
    gsv[i] = (int)(rec & 0x3FFFFu);
    Lv[i]  = (s < nseg) ? (int)(rec >> 18) : 0;
  }
  int lm = max(max(Lv[0], Lv[1]), max(Lv[2], Lv[3]));
  #pragma unroll
  for (int off = 32; off; off >>= 1) lm = max(lm, __shfl_xor(lm, off));

  bf16x8 af[8];

  for (int k = 0; k < lm; k++) {
    if (k == 0) {
      // ---- k=0: h_prev = 0, gh = bh ----
      #pragma unroll
      for (int w = 0; w < 16; w++) {
        int col = w * 16 + lr;
        float bhr = bh[col], bhz = bh[col + 256], bhn = bh[col + 512];
        #pragma unroll
        for (int i = 0; i < 4; i++) {
          int row = g2 * 4 + i;
          float hnew = 0.0f;
          if (Lv[i] > 0) {
            int gidx = gsv[i];
            float gr = bf2f(gx[(size_t)gidx * G3 + col]);
            float gz = bf2f(gx[(size_t)gidx * G3 + 256 + col]);
            float gn = bf2f(gx[(size_t)gidx * G3 + 512 + col]);
            float r = fsig(gr + bhr);
            float z = fsig(gz + bhz);
            float nn = ftanh(gn + r * bhn);
            hnew = (1.0f - z) * nn;
            if (((gidx + 1) & 4095) == 0) {
              float m = 1.0f - is_summ[gidx];
              h_last[(size_t)(gidx >> 12) * HD + col] = m * hnew;
            }
          }
          h[row][HCOL(row, col)] = hnew;
        }
      }
    } else {
      // ---- gh = h_{k-1} @ Wh (af from previous iter) + update ----
      for (int w = 0; w < 16; w++) {
        f32x4 ar = {0,0,0,0}, az = {0,0,0,0}, an = {0,0,0,0};
        const u16* wr = WhT + (size_t)(w * 16 + lr) * HD + lk;
        #pragma unroll
        for (int kk = 0; kk < 8; kk++) {
          bf16x8 b0 = *(const bf16x8*)(wr + kk * 32);
          bf16x8 b1 = *(const bf16x8*)(wr + (size_t)256 * HD + kk * 32);
          bf16x8 b2 = *(const bf16x8*)(wr + (size_t)512 * HD + kk * 32);
          ar = __builtin_amdgcn_mfma_f32_16x16x32_bf16(af[kk], b0, ar, 0, 0, 0);
          az = __builtin_amdgcn_mfma_f32_16x16x32_bf16(af[kk], b1, az, 0, 0, 0);
          an = __builtin_amdgcn_mfma_f32_16x16x32_bf16(af[kk], b2, an, 0, 0, 0);
        }
        int col = w * 16 + lr;
        float bhr = bh[col], bhz = bh[col + 256], bhn = bh[col + 512];
        #pragma unroll
        for (int i = 0; i < 4; i++) {
          if (k < Lv[i]) {
            int row = g2 * 4 + i;
            int gidx = gsv[i] + k;
            float gr = bf2f(gx[(size_t)gidx * G3 + col]);
            float gz = bf2f(gx[(size_t)gidx * G3 + 256 + col]);
            float gn = bf2f(gx[(size_t)gidx * G3 + 512 + col]);
            float hp = h[row][HCOL(row, col)];
            float r = fsig(gr + ar[i] + bhr);
            float z = fsig(gz + az[i] + bhz);
            float nn = ftanh(gn + r * (an[i] + bhn));
            float hnew = (1.0f - z) * nn + z * hp;
            h[row][HCOL(row, col)] = hnew;
            if (((gidx + 1) & 4095) == 0) {
              float m = 1.0f - is_summ[gidx];
              h_last[(size_t)(gidx >> 12) * HD + col] = m * hnew;
            }
          }
        }
      }
    }
    // ---- rebuild af from updated h (wave-private LDS; waitcnt, no barrier) ----
    asm volatile("s_waitcnt lgkmcnt(0)" ::: "memory");
    #pragma unroll
    for (int kk = 0; kk < 8; kk++) {
      float4 u0 = *(const float4*)&h[lr][HCOL(lr, kk * 32 + lk)];
      float4 u1 = *(const float4*)&h[lr][HCOL(lr, kk * 32 + lk + 4)];
      af[kk] = pack8(u0, u1);
    }
    // ---- fused out-GEMM: r_out = h_k @ Wo + bo (WoT direct from L2) ----
    for (int w = 0; w < 16; w++) {
      f32x4 ao = {0,0,0,0};
      const u16* wr = WoT + (size_t)(w * 16 + lr) * HD + lk;
      #pragma unroll
      for (int kk = 0; kk < 8; kk++) {
        bf16x8 bv = *(const bf16x8*)(wr + kk * 32);
        ao = __builtin_amdgcn_mfma_f32_16x16x32_bf16(af[kk], bv, ao, 0, 0, 0);
      }
      int col = w * 16 + lr;
      float bov = bo[col];
      #pragma unroll
      for (int i = 0; i < 4; i++)
        if (k < Lv[i])
          out[(size_t)(gsv[i] + k) * HD + col] = ao[i] + bov;
    }
  }
}

extern "C" void kernel_launch(void* const* d_in, const int* in_sizes, int n_in,
                              void* d_out, int out_size, void* d_ws, size_t ws_size,
                              hipStream_t stream) {
  const int exp_sizes[8] = {BATCH * TSEQ * HD, BATCH * TSEQ, HD * G3, HD * G3,
                            G3, G3, HD * HD, HD};
  if (n_in != 8) return;
  for (int i = 0; i < 8; i++)
    if (in_sizes[i] != exp_sizes[i]) return;

  const float* b_batch = (const float*)d_in[0];
  const float* is_summ = (const float*)d_in[1];
  const float* Wx = (const float*)d_in[2];
  const float* Wh = (const float*)d_in[3];
  const float* bx = (const float*)d_in[4];
  const float* bh = (const float*)d_in[5];
  const float* Wo = (const float*)d_in[6];
  const float* bo = (const float*)d_in[7];

  float* out = (float*)d_out;
  float* h_last = out + (size_t)MROWS * HD;

  char* ws = (char*)d_ws;
  size_t o = 0;
  u16* gx     = (u16*)(ws + o); o += (size_t)MROWS * G3 * 2;   // 402,653,184
  u16* Abf    = (u16*)(ws + o); o += (size_t)MROWS * HD * 2;   // 134,217,728
  u16* WxT    = (u16*)(ws + o); o += (size_t)G3 * HD * 2;
  u16* WhT    = (u16*)(ws + o); o += (size_t)G3 * HD * 2;
  u16* WoT    = (u16*)(ws + o); o += (size_t)HD * HD * 2;
  int* meta   = (int*)(ws + o); o += 1024;
  u32* tmp    = (u32*)(ws + o); o += (size_t)MROWS * 4;
  u32* sorted = (u32*)(ws + o); o += (size_t)MROWS * 4;
  if (ws_size < o) return;

  k_prep2<<<112, 256, 0, stream>>>(Wx, Wh, Wo, WxT, WhT, WoT, meta);
  k_conv<<<2048, 256, 0, stream>>>(b_batch, Abf);
  k_find<<<MROWS / 256, 256, 0, stream>>>(is_summ, tmp, meta);
  k_buckets<<<1, 64, 0, stream>>>(meta);
  k_scatter<<<256, 256, 0, stream>>>(tmp, sorted, meta);
  k_gemm<G3><<<(MROWS / 128) * (G3 / 64), 256, 0, stream>>>(Abf, WxT, bx, gx);
  k_scan5<<<MROWS / 16, 64, 0, stream>>>(gx, WhT, WoT, bh, bo, is_summ,
                                         out, h_last, sorted, meta);
}